// Round 10
// baseline (6455.345 us; speedup 1.0000x reference)
//
#include <hip/hip_runtime.h>

typedef __bf16 bf16x8 __attribute__((ext_vector_type(8)));
typedef float  f32x4  __attribute__((ext_vector_type(4)));
typedef unsigned short u16;
typedef unsigned int   u32;
typedef unsigned long long u64;

#define NB 128      // batch
#define NT 1024     // time steps
#define NF 128      // input features
#define NH 256      // hidden units
#define NG 1024     // 4*NH gate columns
#define M_ROWS (NB*NT)
#define SENT (~0ull)   // sentinel: 4x bf16 0xFFFF (NaN) -- unreachable as h data

__device__ __forceinline__ u16 f2bf(float f) {
  union { float f; u32 u; } c; c.f = f;
  u32 u = c.u;
  return (u16)((u + 0x7fffu + ((u >> 16) & 1u)) >> 16);   // RNE
}
__device__ __forceinline__ float sigm(float x) { return 1.f / (1.f + __expf(-x)); }
__device__ __forceinline__ float tanh_(float x) { return 1.f - 2.f / (1.f + __expf(2.f * x)); }
__device__ __forceinline__ f32x4 mm(bf16x8 a, bf16x8 b, f32x4 c) {
  return __builtin_amdgcn_mfma_f32_16x16x32_bf16(a, b, c, 0, 0, 0);
}

// Relaxed AGENT atomics: MALL coherence point by scope, no cache-maintenance.
// (HW-proven data path, rounds 4-9.)
__device__ __forceinline__ u64 a_ld64(const u64* p) { return __hip_atomic_load((u64*)p, __ATOMIC_RELAXED, __HIP_MEMORY_SCOPE_AGENT); }
__device__ __forceinline__ void a_st64(u64* p, u64 v) { __hip_atomic_store(p, v, __ATOMIC_RELAXED, __HIP_MEMORY_SCOPE_AGENT); }

// ---------------------------------------------------------------------------
// prep: sentinel-fill hseq (64 MiB) + h2 (256 KiB). Runs every launch ->
// also erases stale data from prior replays.
// ---------------------------------------------------------------------------
__global__ void prep(u64* __restrict__ hseq, u64* __restrict__ h2) {
  long i = (long)blockIdx.x * 256 + threadIdx.x;
  if (i < (long)M_ROWS * 64) a_st64(hseq + i, SENT);
  if (i < 4L * 8 * 16 * 64)  a_st64(h2 + i, SENT);
}

// ---------------------------------------------------------------------------
// Fused 2-layer LSTM scan, SENTINEL protocol (R9) + ISSUE-EARLY/WAIT-LATE:
// every long-latency load of a step (exchange sentinels, x HBM reads, feed)
// is issued speculatively at the TOP of the step; the sentinel check (and its
// vmcnt wait) happens after the independent compute that can run meanwhile.
// Re-poll loops fire only on a miss. Protocol, buffers, wipe logic: R9-exact.
// ---------------------------------------------------------------------------
template<bool IS1>
__device__ void scan(const float* __restrict__ U, const float* __restrict__ W,
                     const float* __restrict__ bias, const float* __restrict__ xf,
                     u64* hseq, u64* h2, float* hlast,
                     int g, int j, float (*gl)[16][68])
{
  const int tid = threadIdx.x, lane = tid & 63, w = tid >> 6;
  const int l15 = lane & 15, l16 = lane >> 4;
  constexpr int KIN  = IS1 ? NF : NH;
  constexpr int KTIN = KIN / 32;
  const int colb = w * NH + j * 64;

  // Resident W frags (B-operand), K = KIN
  bf16x8 wfr[KTIN][4];
#pragma unroll
  for (int kt = 0; kt < KTIN; ++kt) {
    const int k0 = kt * 32 + l16 * 8;
#pragma unroll
    for (int nt = 0; nt < 4; ++nt) {
      const float* wp = W + (long)k0 * NG + colb + nt * 16 + l15;
      union { u16 s[8]; bf16x8 v; } cv;
#pragma unroll
      for (int e = 0; e < 8; ++e) cv.s[e] = f2bf(wp[(long)e * NG]);
      wfr[kt][nt] = cv.v;
    }
  }
  // Resident U frags (B-operand), K = NH
  bf16x8 ufr[8][4];
#pragma unroll
  for (int kt = 0; kt < 8; ++kt) {
    const int k0 = kt * 32 + l16 * 8;
#pragma unroll
    for (int nt = 0; nt < 4; ++nt) {
      const float* up = U + (long)k0 * NG + colb + nt * 16 + l15;
      union { u16 s[8]; bf16x8 v; } cv;
#pragma unroll
      for (int e = 0; e < 8; ++e) cv.s[e] = f2bf(up[(long)e * NG]);
      ufr[kt][nt] = cv.v;
    }
  }
  // Pin frags (live in unified VGPR/AGPR file; prevents remat-by-reload).
#pragma unroll
  for (int kt = 0; kt < KTIN; ++kt)
#pragma unroll
    for (int nt = 0; nt < 4; ++nt)
      asm volatile("" : "+v"(wfr[kt][nt]));
#pragma unroll
  for (int kt = 0; kt < 8; ++kt)
#pragma unroll
    for (int nt = 0; nt < 4; ++nt)
      asm volatile("" : "+v"(ufr[kt][nt]));

  const int prow = tid & 15, ublk = tid >> 4;
  const int b = g * 16 + prow, ucol = j * 64 + ublk * 4;

  float bv[4][4];
#pragma unroll
  for (int gg = 0; gg < 4; ++gg)
#pragma unroll
    for (int q = 0; q < 4; ++q) bv[gg][q] = bias[gg * NH + ucol + q];

  const long abatch = (long)(g * 16 + l15) * NT;

  float cst[4] = {0.f, 0.f, 0.f, 0.f};
  long budget = 500000;   // re-poll iterations; bail, never hang

  for (int t = 0; t < NT; ++t) {
    bf16x8 ax[KTIN];
    f32x4 acc[4] = {};

    if constexpr (IS1) {
      // ---- TOP: speculative issue of rec sentinels, then x loads ----
      const u64* hb = hseq + (abatch + (t - 1)) * 64;
      u64 hr[8][2];
      if (t > 0) {
#pragma unroll
        for (int kt = 0; kt < 8; ++kt) {
          hr[kt][0] = a_ld64(hb + kt * 8 + l16 * 2);
          hr[kt][1] = a_ld64(hb + kt * 8 + l16 * 2 + 1);
        }
      }
      const float* xp0 = xf + (abatch + t) * NF;
      f32x4 xraw[KTIN][2];
#pragma unroll
      for (int kt = 0; kt < KTIN; ++kt) {
        const float* xp = xp0 + kt * 32 + l16 * 8;
        xraw[kt][0] = *reinterpret_cast<const f32x4*>(xp);
        xraw[kt][1] = *reinterpret_cast<const f32x4*>(xp + 4);
      }
      // ---- x path (hides both x HBM latency and rec exchange flight) ----
#pragma unroll
      for (int kt = 0; kt < KTIN; ++kt) {
        union { u16 s[8]; bf16x8 v; } cv;
#pragma unroll
        for (int e = 0; e < 4; ++e) {
          cv.s[e] = f2bf(xraw[kt][0][e]); cv.s[4 + e] = f2bf(xraw[kt][1][e]);
        }
        ax[kt] = cv.v;
      }
#pragma unroll
      for (int kt = 0; kt < KTIN; ++kt)
#pragma unroll
        for (int nt = 0; nt < 4; ++nt) acc[nt] = mm(ax[kt], wfr[kt][nt], acc[nt]);

      // ---- LATE: rec sentinel check; re-poll only on miss ----
      if (t > 0) {
        bool ok = true;
#pragma unroll
        for (int kt = 0; kt < 8; ++kt)
          ok = ok && (hr[kt][0] != SENT) && (hr[kt][1] != SENT);
        while (!__all(ok ? 1 : 0)) {
          if (--budget <= 0) break;
#pragma unroll
          for (int kt = 0; kt < 8; ++kt) {
            hr[kt][0] = a_ld64(hb + kt * 8 + l16 * 2);
            hr[kt][1] = a_ld64(hb + kt * 8 + l16 * 2 + 1);
          }
          ok = true;
#pragma unroll
          for (int kt = 0; kt < 8; ++kt)
            ok = ok && (hr[kt][0] != SENT) && (hr[kt][1] != SENT);
        }
        asm volatile("" ::: "memory");
#pragma unroll
        for (int kt = 0; kt < 8; ++kt) {
          union { u64 q[2]; bf16x8 v; } cv;
          cv.q[0] = hr[kt][0]; cv.q[1] = hr[kt][1];
#pragma unroll
          for (int nt = 0; nt < 4; ++nt) acc[nt] = mm(cv.v, ufr[kt][nt], acc[nt]);
        }
      }
    } else {
      // ---- TOP: speculative issue of rec (h2) then feed (hseq) loads ----
      const u64* xb = hseq + (abatch + t) * 64;
      const u64* hb = h2 + (((long)((t + 3) & 3) * 8 + g) * 16 + l15) * 64;
      u64 xr[8][2], hr[8][2];
      if (t > 0) {
#pragma unroll
        for (int kt = 0; kt < 8; ++kt) {
          hr[kt][0] = a_ld64(hb + kt * 8 + l16 * 2);
          hr[kt][1] = a_ld64(hb + kt * 8 + l16 * 2 + 1);
        }
      }
#pragma unroll
      for (int kt = 0; kt < 8; ++kt) {
        xr[kt][0] = a_ld64(xb + kt * 8 + l16 * 2);
        xr[kt][1] = a_ld64(xb + kt * 8 + l16 * 2 + 1);
      }
      // ---- feed check + re-poll (rec loads remain in flight) ----
      {
        bool ok = true;
#pragma unroll
        for (int kt = 0; kt < 8; ++kt)
          ok = ok && (xr[kt][0] != SENT) && (xr[kt][1] != SENT);
        while (!__all(ok ? 1 : 0)) {
          if (--budget <= 0) break;
#pragma unroll
          for (int kt = 0; kt < 8; ++kt) {
            xr[kt][0] = a_ld64(xb + kt * 8 + l16 * 2);
            xr[kt][1] = a_ld64(xb + kt * 8 + l16 * 2 + 1);
          }
          ok = true;
#pragma unroll
          for (int kt = 0; kt < 8; ++kt)
            ok = ok && (xr[kt][0] != SENT) && (xr[kt][1] != SENT);
        }
        asm volatile("" ::: "memory");
      }
      // ---- feed MFMAs (hide rec flight) ----
#pragma unroll
      for (int kt = 0; kt < KTIN; ++kt) {
        union { u64 q[2]; bf16x8 v; } cv;
        cv.q[0] = xr[kt][0]; cv.q[1] = xr[kt][1];
        ax[kt] = cv.v;
      }
#pragma unroll
      for (int kt = 0; kt < KTIN; ++kt)
#pragma unroll
        for (int nt = 0; nt < 4; ++nt) acc[nt] = mm(ax[kt], wfr[kt][nt], acc[nt]);

      // ---- LATE: rec check + re-poll + MFMAs ----
      if (t > 0) {
        bool ok = true;
#pragma unroll
        for (int kt = 0; kt < 8; ++kt)
          ok = ok && (hr[kt][0] != SENT) && (hr[kt][1] != SENT);
        while (!__all(ok ? 1 : 0)) {
          if (--budget <= 0) break;
#pragma unroll
          for (int kt = 0; kt < 8; ++kt) {
            hr[kt][0] = a_ld64(hb + kt * 8 + l16 * 2);
            hr[kt][1] = a_ld64(hb + kt * 8 + l16 * 2 + 1);
          }
          ok = true;
#pragma unroll
          for (int kt = 0; kt < 8; ++kt)
            ok = ok && (hr[kt][0] != SENT) && (hr[kt][1] != SENT);
        }
        asm volatile("" ::: "memory");
#pragma unroll
        for (int kt = 0; kt < 8; ++kt) {
          union { u64 q[2]; bf16x8 v; } cv;
          cv.q[0] = hr[kt][0]; cv.q[1] = hr[kt][1];
#pragma unroll
          for (int nt = 0; nt < 4; ++nt) acc[nt] = mm(cv.v, ufr[kt][nt], acc[nt]);
        }
      }
    }

    // ---- gate tiles -> LDS (cross-wave exchange); 2 barriers (R9) ----
#pragma unroll
    for (int nt = 0; nt < 4; ++nt)
#pragma unroll
      for (int r = 0; r < 4; ++r)
        gl[w][l16 * 4 + r][nt * 16 + l15] = acc[nt][r];
    __syncthreads();
    f32x4 gi = *reinterpret_cast<const f32x4*>(&gl[0][prow][ublk * 4]);
    f32x4 gf = *reinterpret_cast<const f32x4*>(&gl[1][prow][ublk * 4]);
    f32x4 gc = *reinterpret_cast<const f32x4*>(&gl[2][prow][ublk * 4]);
    f32x4 go = *reinterpret_cast<const f32x4*>(&gl[3][prow][ublk * 4]);
    __syncthreads();

    // ---- pointwise cell update (Keras order i, f, cbar, o) ----
    float hh[4];
#pragma unroll
    for (int q = 0; q < 4; ++q) {
      float iv = sigm(gi[q] + bv[0][q]);
      float fv = sigm(gf[q] + bv[1][q]);
      float cd = tanh_(gc[q] + bv[2][q]);
      float ov = sigm(go[q] + bv[3][q]);
      cst[q] = fv * cst[q] + iv * cd;
      hh[q] = ov * tanh_(cst[q]);
    }
    union { u16 s[4]; u64 q; } hp;
#pragma unroll
    for (int q = 0; q < 4; ++q) hp.s[q] = f2bf(hh[q]);

    // ---- publish h_t: fire-and-forget atomic store (R9-exact) ----
    if constexpr (IS1) {
      a_st64(hseq + ((long)b * NT + t) * 64 + (ucol >> 2), hp.q);
    } else {
      a_st64(h2 + (((long)(t & 3) * 8 + g) * 16 + prow) * 64 + (ucol >> 2), hp.q);
      // wipe own chunk of slot (t+1)&3 (holds t-3 data; readers provably done)
      a_st64(h2 + (((long)((t + 1) & 3) * 8 + g) * 16 + prow) * 64 + (ucol >> 2), SENT);
      if (t == NT - 1)
        *reinterpret_cast<f32x4*>(hlast + (long)b * NH + ucol) =
            f32x4{hh[0], hh[1], hh[2], hh[3]};
    }
  }
}

// ---------------------------------------------------------------------------
__global__ __launch_bounds__(256, 1) void lstm_fused(
    const float* __restrict__ x,
    const float* __restrict__ W1, const float* __restrict__ U1, const float* __restrict__ b1,
    const float* __restrict__ W2, const float* __restrict__ U2, const float* __restrict__ b2,
    u64* hseq, u64* h2, float* hlast)
{
  __shared__ __align__(16) float gl[4][16][68];
  const int bid = blockIdx.x;
  const int sb  = bid & 31, g = sb & 7, j = sb >> 3;
  if (bid < 32)
    scan<true >(U1, W1, b1, x, hseq, h2, nullptr, g, j, gl);
  else
    scan<false>(U2, W2, b2, nullptr, hseq, h2, hlast, g, j, gl);
}

// ---------------------------------------------------------------------------
__global__ void dense_out(const float* __restrict__ hl, const float* __restrict__ Wd,
                          const float* __restrict__ bd, float* __restrict__ out) {
  int b = blockIdx.x, l = threadIdx.x;
  f32x4 h  = *reinterpret_cast<const f32x4*>(hl + (long)b * NH + l * 4);
  f32x4 wv = *reinterpret_cast<const f32x4*>(Wd + l * 4);
  float s = h[0] * wv[0] + h[1] * wv[1] + h[2] * wv[2] + h[3] * wv[3];
#pragma unroll
  for (int off = 32; off > 0; off >>= 1) s += __shfl_down(s, off);
  if (l == 0) out[b] = fmaxf(s + bd[0], 0.f);
}

// ---------------------------------------------------------------------------
extern "C" void kernel_launch(void* const* d_in, const int* in_sizes, int n_in,
                              void* d_out, int out_size, void* d_ws, size_t ws_size,
                              hipStream_t stream) {
  const float* x  = (const float*)d_in[0];
  const float* W1 = (const float*)d_in[1];
  const float* U1 = (const float*)d_in[2];
  const float* b1 = (const float*)d_in[3];
  const float* W2 = (const float*)d_in[4];
  const float* U2 = (const float*)d_in[5];
  const float* b2 = (const float*)d_in[6];
  const float* Wd = (const float*)d_in[7];
  const float* bd = (const float*)d_in[8];
  float* out = (float*)d_out;

  char* ws = (char*)d_ws;
  size_t off = 0;
  auto alloc = [&](size_t bytes) -> char* {
    char* p = ws + off;
    off = (off + bytes + 255) & ~(size_t)255;
    return p;
  };
  u64*   hseq  = (u64*)  alloc((size_t)M_ROWS * NH * 2);       // 64 MiB
  u64*   h2    = (u64*)  alloc((size_t)4 * 8 * 16 * NH * 2);   // 256 KiB
  float* hlast = (float*)alloc((size_t)NB * NH * 4);           // 128 KiB

  if (off > ws_size) {
    // workspace too small: finite sentinel 0x42424242 ~= 48.56 (NOT NaN)
    hipMemsetAsync(d_out, 0x42, (size_t)out_size * sizeof(float), stream);
    return;
  }

  prep<<<32768, 256, 0, stream>>>(hseq, h2);
  lstm_fused<<<64, 256, 0, stream>>>(x, W1, U1, b1, W2, U2, b2, hseq, h2, hlast);
  dense_out<<<128, 64, 0, stream>>>(hlast, Wd, bd, out);
}

// Round 11
// 5676.496 us; speedup vs baseline: 1.1372x; 1.1372x over previous
//
#include <hip/hip_runtime.h>

typedef __bf16 bf16x8 __attribute__((ext_vector_type(8)));
typedef float  f32x4  __attribute__((ext_vector_type(4)));
typedef unsigned short u16;
typedef unsigned int   u32;
typedef unsigned long long u64;

#define NB 128      // batch
#define NT 1024     // time steps
#define NF 128      // input features
#define NH 256      // hidden units
#define NG 1024     // 4*NH gate columns
#define M_ROWS (NB*NT)
#define SENT (~0ull)   // sentinel: 4x bf16 0xFFFF (NaN) -- unreachable as h data

__device__ __forceinline__ u16 f2bf(float f) {
  union { float f; u32 u; } c; c.f = f;
  u32 u = c.u;
  return (u16)((u + 0x7fffu + ((u >> 16) & 1u)) >> 16);   // RNE
}
__device__ __forceinline__ float sigm(float x) { return 1.f / (1.f + __expf(-x)); }
__device__ __forceinline__ float tanh_(float x) { return 1.f - 2.f / (1.f + __expf(2.f * x)); }
__device__ __forceinline__ f32x4 mm(bf16x8 a, bf16x8 b, f32x4 c) {
  return __builtin_amdgcn_mfma_f32_16x16x32_bf16(a, b, c, 0, 0, 0);
}

// Relaxed AGENT atomics: MALL coherence point by scope, no cache-maintenance.
// (HW-proven data path, rounds 4-10.)
__device__ __forceinline__ u64 a_ld64(const u64* p) { return __hip_atomic_load((u64*)p, __ATOMIC_RELAXED, __HIP_MEMORY_SCOPE_AGENT); }
__device__ __forceinline__ void a_st64(u64* p, u64 v) { __hip_atomic_store(p, v, __ATOMIC_RELAXED, __HIP_MEMORY_SCOPE_AGENT); }

// ---------------------------------------------------------------------------
// prep: sentinel-fill hseq (64 MiB) + h2 (256 KiB). Runs every launch ->
// also erases stale data from prior replays.
// ---------------------------------------------------------------------------
__global__ void prep(u64* __restrict__ hseq, u64* __restrict__ h2) {
  long i = (long)blockIdx.x * 256 + threadIdx.x;
  if (i < (long)M_ROWS * 64) a_st64(hseq + i, SENT);
  if (i < 4L * 8 * 16 * 64)  a_st64(h2 + i, SENT);
}

// ---------------------------------------------------------------------------
// Fused 2-layer LSTM scan, SENTINEL protocol (R9-exact) with gl double-
// buffered by step parity -> ONE barrier per step (R9 had two).
//   producer: a_st64 h chunks, fire-and-forget.
//   consumer: poll the data words themselves until != SENT (detect == data).
// Buffers: hseq [NB,NT,NH] bf16 write-once; h2 4-deep [4][8][16][NH] bf16,
// each L2 WG re-sentinels its chunk of slot (t+1)&3 per step.
// 64 WGs: bid<32 -> L1, else L2; 8 groups x 4 WGs x 4 waves (wave = gate).
// ---------------------------------------------------------------------------
template<bool IS1>
__device__ void scan(const float* __restrict__ U, const float* __restrict__ W,
                     const float* __restrict__ bias, const float* __restrict__ xf,
                     u64* hseq, u64* h2, float* hlast,
                     int g, int j, float (*gl)[4][16][68])
{
  const int tid = threadIdx.x, lane = tid & 63, w = tid >> 6;
  const int l15 = lane & 15, l16 = lane >> 4;
  constexpr int KIN  = IS1 ? NF : NH;
  constexpr int KTIN = KIN / 32;
  const int colb = w * NH + j * 64;

  // Resident W frags (B-operand), K = KIN
  bf16x8 wfr[KTIN][4];
#pragma unroll
  for (int kt = 0; kt < KTIN; ++kt) {
    const int k0 = kt * 32 + l16 * 8;
#pragma unroll
    for (int nt = 0; nt < 4; ++nt) {
      const float* wp = W + (long)k0 * NG + colb + nt * 16 + l15;
      union { u16 s[8]; bf16x8 v; } cv;
#pragma unroll
      for (int e = 0; e < 8; ++e) cv.s[e] = f2bf(wp[(long)e * NG]);
      wfr[kt][nt] = cv.v;
    }
  }
  // Resident U frags (B-operand), K = NH
  bf16x8 ufr[8][4];
#pragma unroll
  for (int kt = 0; kt < 8; ++kt) {
    const int k0 = kt * 32 + l16 * 8;
#pragma unroll
    for (int nt = 0; nt < 4; ++nt) {
      const float* up = U + (long)k0 * NG + colb + nt * 16 + l15;
      union { u16 s[8]; bf16x8 v; } cv;
#pragma unroll
      for (int e = 0; e < 8; ++e) cv.s[e] = f2bf(up[(long)e * NG]);
      ufr[kt][nt] = cv.v;
    }
  }
  // Pin frags (unified VGPR/AGPR file; prevents remat-by-reload).
#pragma unroll
  for (int kt = 0; kt < KTIN; ++kt)
#pragma unroll
    for (int nt = 0; nt < 4; ++nt)
      asm volatile("" : "+v"(wfr[kt][nt]));
#pragma unroll
  for (int kt = 0; kt < 8; ++kt)
#pragma unroll
    for (int nt = 0; nt < 4; ++nt)
      asm volatile("" : "+v"(ufr[kt][nt]));

  const int prow = tid & 15, ublk = tid >> 4;
  const int b = g * 16 + prow, ucol = j * 64 + ublk * 4;

  float bv[4][4];
#pragma unroll
  for (int gg = 0; gg < 4; ++gg)
#pragma unroll
    for (int q = 0; q < 4; ++q) bv[gg][q] = bias[gg * NH + ucol + q];

  const long abatch = (long)(g * 16 + l15) * NT;

  float cst[4] = {0.f, 0.f, 0.f, 0.f};
  long budget = 500000;   // poll iterations; bail, never hang

  for (int t = 0; t < NT; ++t) {
    bf16x8 ax[KTIN];
    f32x4 acc[4] = {};
    const int p = t & 1;   // gl parity

    if constexpr (IS1) {
      // ---- x loads + cvt + x@W MFMAs (overlaps producers' store flight) ----
      const float* xp0 = xf + (abatch + t) * NF;
      f32x4 xraw[KTIN][2];
#pragma unroll
      for (int kt = 0; kt < KTIN; ++kt) {
        const float* xp = xp0 + kt * 32 + l16 * 8;
        xraw[kt][0] = *reinterpret_cast<const f32x4*>(xp);
        xraw[kt][1] = *reinterpret_cast<const f32x4*>(xp + 4);
      }
#pragma unroll
      for (int kt = 0; kt < KTIN; ++kt) {
        union { u16 s[8]; bf16x8 v; } cv;
#pragma unroll
        for (int e = 0; e < 4; ++e) {
          cv.s[e] = f2bf(xraw[kt][0][e]); cv.s[4 + e] = f2bf(xraw[kt][1][e]);
        }
        ax[kt] = cv.v;
      }
#pragma unroll
      for (int kt = 0; kt < KTIN; ++kt)
#pragma unroll
        for (int nt = 0; nt < 4; ++nt) acc[nt] = mm(ax[kt], wfr[kt][nt], acc[nt]);

      // ---- sentinel-poll h_{t-1} (detect == data) + U MFMAs ----
      if (t > 0) {
        const u64* hb = hseq + (abatch + (t - 1)) * 64;
        u64 hr[8][2];
        for (;;) {
          bool ok = true;
#pragma unroll
          for (int kt = 0; kt < 8; ++kt) {
            hr[kt][0] = a_ld64(hb + kt * 8 + l16 * 2);
            hr[kt][1] = a_ld64(hb + kt * 8 + l16 * 2 + 1);
          }
#pragma unroll
          for (int kt = 0; kt < 8; ++kt)
            ok = ok && (hr[kt][0] != SENT) && (hr[kt][1] != SENT);
          if (__all(ok ? 1 : 0)) break;
          if (--budget <= 0) break;
        }
        asm volatile("" ::: "memory");
#pragma unroll
        for (int kt = 0; kt < 8; ++kt) {
          union { u64 q[2]; bf16x8 v; } cv;
          cv.q[0] = hr[kt][0]; cv.q[1] = hr[kt][1];
#pragma unroll
          for (int nt = 0; nt < 4; ++nt) acc[nt] = mm(cv.v, ufr[kt][nt], acc[nt]);
        }
      }
    } else {
      // ---- L2: ONE sentinel-poll over feed (hseq[t]) + rec (h2 slot) ----
      const u64* xb = hseq + (abatch + t) * 64;
      const u64* hb = h2 + (((long)((t + 3) & 3) * 8 + g) * 16 + l15) * 64;
      u64 xr[8][2], hr[8][2];
      for (;;) {
        bool ok = true;
#pragma unroll
        for (int kt = 0; kt < 8; ++kt) {
          xr[kt][0] = a_ld64(xb + kt * 8 + l16 * 2);
          xr[kt][1] = a_ld64(xb + kt * 8 + l16 * 2 + 1);
        }
#pragma unroll
        for (int kt = 0; kt < 8; ++kt)
          ok = ok && (xr[kt][0] != SENT) && (xr[kt][1] != SENT);
        if (t > 0) {
#pragma unroll
          for (int kt = 0; kt < 8; ++kt) {
            hr[kt][0] = a_ld64(hb + kt * 8 + l16 * 2);
            hr[kt][1] = a_ld64(hb + kt * 8 + l16 * 2 + 1);
          }
#pragma unroll
          for (int kt = 0; kt < 8; ++kt)
            ok = ok && (hr[kt][0] != SENT) && (hr[kt][1] != SENT);
        }
        if (__all(ok ? 1 : 0)) break;
        if (--budget <= 0) break;
      }
      asm volatile("" ::: "memory");
#pragma unroll
      for (int kt = 0; kt < KTIN; ++kt) {
        union { u64 q[2]; bf16x8 v; } cv;
        cv.q[0] = xr[kt][0]; cv.q[1] = xr[kt][1];
        ax[kt] = cv.v;
      }
#pragma unroll
      for (int kt = 0; kt < KTIN; ++kt)
#pragma unroll
        for (int nt = 0; nt < 4; ++nt) acc[nt] = mm(ax[kt], wfr[kt][nt], acc[nt]);
      if (t > 0) {
#pragma unroll
        for (int kt = 0; kt < 8; ++kt) {
          union { u64 q[2]; bf16x8 v; } cv;
          cv.q[0] = hr[kt][0]; cv.q[1] = hr[kt][1];
#pragma unroll
          for (int nt = 0; nt < 4; ++nt) acc[nt] = mm(cv.v, ufr[kt][nt], acc[nt]);
        }
      }
    }

    // ---- gate tiles -> LDS (cross-wave exchange), parity-buffered ----
    // One barrier/step: step t+2's writes to parity p are separated from
    // step t's reads of parity p by step t+1's barrier (each wave's t+1
    // writes follow its t reads in program order).
#pragma unroll
    for (int nt = 0; nt < 4; ++nt)
#pragma unroll
      for (int r = 0; r < 4; ++r)
        gl[p][w][l16 * 4 + r][nt * 16 + l15] = acc[nt][r];
    __syncthreads();
    f32x4 gi = *reinterpret_cast<const f32x4*>(&gl[p][0][prow][ublk * 4]);
    f32x4 gf = *reinterpret_cast<const f32x4*>(&gl[p][1][prow][ublk * 4]);
    f32x4 gc = *reinterpret_cast<const f32x4*>(&gl[p][2][prow][ublk * 4]);
    f32x4 go = *reinterpret_cast<const f32x4*>(&gl[p][3][prow][ublk * 4]);

    // ---- pointwise cell update (Keras order i, f, cbar, o) ----
    float hh[4];
#pragma unroll
    for (int q = 0; q < 4; ++q) {
      float iv = sigm(gi[q] + bv[0][q]);
      float fv = sigm(gf[q] + bv[1][q]);
      float cd = tanh_(gc[q] + bv[2][q]);
      float ov = sigm(go[q] + bv[3][q]);
      cst[q] = fv * cst[q] + iv * cd;
      hh[q] = ov * tanh_(cst[q]);
    }
    union { u16 s[4]; u64 q; } hp;
#pragma unroll
    for (int q = 0; q < 4; ++q) hp.s[q] = f2bf(hh[q]);

    // ---- publish h_t: fire-and-forget atomic store (R9-exact) ----
    if constexpr (IS1) {
      a_st64(hseq + ((long)b * NT + t) * 64 + (ucol >> 2), hp.q);
    } else {
      a_st64(h2 + (((long)(t & 3) * 8 + g) * 16 + prow) * 64 + (ucol >> 2), hp.q);
      // wipe own chunk of slot (t+1)&3 (holds t-3 data; readers provably done)
      a_st64(h2 + (((long)((t + 1) & 3) * 8 + g) * 16 + prow) * 64 + (ucol >> 2), SENT);
      if (t == NT - 1)
        *reinterpret_cast<f32x4*>(hlast + (long)b * NH + ucol) =
            f32x4{hh[0], hh[1], hh[2], hh[3]};
    }
  }
}

// ---------------------------------------------------------------------------
__global__ __launch_bounds__(256, 1) void lstm_fused(
    const float* __restrict__ x,
    const float* __restrict__ W1, const float* __restrict__ U1, const float* __restrict__ b1,
    const float* __restrict__ W2, const float* __restrict__ U2, const float* __restrict__ b2,
    u64* hseq, u64* h2, float* hlast)
{
  __shared__ __align__(16) float gl[2][4][16][68];   // parity double-buffer
  const int bid = blockIdx.x;
  const int sb  = bid & 31, g = sb & 7, j = sb >> 3;
  if (bid < 32)
    scan<true >(U1, W1, b1, x, hseq, h2, nullptr, g, j, gl);
  else
    scan<false>(U2, W2, b2, nullptr, hseq, h2, hlast, g, j, gl);
}

// ---------------------------------------------------------------------------
__global__ void dense_out(const float* __restrict__ hl, const float* __restrict__ Wd,
                          const float* __restrict__ bd, float* __restrict__ out) {
  int b = blockIdx.x, l = threadIdx.x;
  f32x4 h  = *reinterpret_cast<const f32x4*>(hl + (long)b * NH + l * 4);
  f32x4 wv = *reinterpret_cast<const f32x4*>(Wd + l * 4);
  float s = h[0] * wv[0] + h[1] * wv[1] + h[2] * wv[2] + h[3] * wv[3];
#pragma unroll
  for (int off = 32; off > 0; off >>= 1) s += __shfl_down(s, off);
  if (l == 0) out[b] = fmaxf(s + bd[0], 0.f);
}

// ---------------------------------------------------------------------------
extern "C" void kernel_launch(void* const* d_in, const int* in_sizes, int n_in,
                              void* d_out, int out_size, void* d_ws, size_t ws_size,
                              hipStream_t stream) {
  const float* x  = (const float*)d_in[0];
  const float* W1 = (const float*)d_in[1];
  const float* U1 = (const float*)d_in[2];
  const float* b1 = (const float*)d_in[3];
  const float* W2 = (const float*)d_in[4];
  const float* U2 = (const float*)d_in[5];
  const float* b2 = (const float*)d_in[6];
  const float* Wd = (const float*)d_in[7];
  const float* bd = (const float*)d_in[8];
  float* out = (float*)d_out;

  char* ws = (char*)d_ws;
  size_t off = 0;
  auto alloc = [&](size_t bytes) -> char* {
    char* p = ws + off;
    off = (off + bytes + 255) & ~(size_t)255;
    return p;
  };
  u64*   hseq  = (u64*)  alloc((size_t)M_ROWS * NH * 2);       // 64 MiB
  u64*   h2    = (u64*)  alloc((size_t)4 * 8 * 16 * NH * 2);   // 256 KiB
  float* hlast = (float*)alloc((size_t)NB * NH * 4);           // 128 KiB

  if (off > ws_size) {
    // workspace too small: finite sentinel 0x42424242 ~= 48.56 (NOT NaN)
    hipMemsetAsync(d_out, 0x42, (size_t)out_size * sizeof(float), stream);
    return;
  }

  prep<<<32768, 256, 0, stream>>>(hseq, h2);
  lstm_fused<<<64, 256, 0, stream>>>(x, W1, U1, b1, W2, U2, b2, hseq, h2, hlast);
  dense_out<<<128, 64, 0, stream>>>(hlast, Wd, bd, out);
}